// Round 10
// baseline (311.201 us; speedup 1.0000x reference)
//
#include <hip/hip_runtime.h>

#define D 128
#define RS_STRIDE 64      // floats (256 B) between result slots

typedef __attribute__((ext_vector_type(8))) short bf16x8;
typedef __attribute__((ext_vector_type(8))) unsigned short u16x8;
typedef __attribute__((ext_vector_type(4))) float f32x4;
typedef __attribute__((ext_vector_type(2))) float f32x2;

__device__ __forceinline__ unsigned short f2bf(float f) {
    unsigned u = __float_as_uint(f);
    unsigned r = (u + 0x7fffu + ((u >> 16) & 1u)) >> 16;
    return (unsigned short)r;
}
__device__ __forceinline__ ushort4 pack4(float4 v) {
    ushort4 o; o.x = f2bf(v.x); o.y = f2bf(v.y); o.z = f2bf(v.z); o.w = f2bf(v.w);
    return o;
}
__device__ __forceinline__ void red3(float& x) {
    x += __shfl_xor(x, 8);
    x += __shfl_xor(x, 16);
    x += __shfl_xor(x, 32);
}
// fp8 e4m3 x4 (one dword) decode-accumulate into 4 fp32 slots (HW cvt).
__device__ __forceinline__ void acc4(unsigned v, float* s) {
    f32x2 lo = __builtin_amdgcn_cvt_pk_f32_fp8(v, false);
    f32x2 hi = __builtin_amdgcn_cvt_pk_f32_fp8(v, true);
    s[0] += lo[0]; s[1] += lo[1]; s[2] += hi[0]; s[3] += hi[1];
}
__device__ __forceinline__ void acc16(uint4 v, float* s) {
    acc4(v.x, s); acc4(v.y, s + 4); acc4(v.z, s + 8); acc4(v.w, s + 12);
}
// LDS tile swizzle: 16B slot s (0..15) of row r -> slot s^(r&7).
__device__ __forceinline__ int swz(int r, int s) {
    return r * D + ((s ^ (r & 7)) << 3);     // ushort index
}

// -------------------------------------------------------------------------
// Fused prep: emb fp32->fp8 e4m3 row-major (if n4>0), W/M fp32->bf16,
// zero rs slots + done counter, row_ptr[N+1] from sorted segment_ids.
__global__ void prep_kernel(const float* __restrict__ emb, const float* __restrict__ W,
                            const float* __restrict__ M, const int* __restrict__ seg,
                            unsigned char* __restrict__ emb8,
                            unsigned short* __restrict__ Wb, unsigned short* __restrict__ Mb,
                            float* __restrict__ rs, int* __restrict__ row_ptr,
                            unsigned* __restrict__ done, int n4, int E, int N) {
    int i = blockIdx.x * blockDim.x + threadIdx.x;
    if (i < n4) {
        float4 v = ((const float4*)emb)[i];
        int p = __builtin_amdgcn_cvt_pk_fp8_f32(v.x, v.y, 0, false);
        p = __builtin_amdgcn_cvt_pk_fp8_f32(v.z, v.w, p, true);
        ((unsigned*)emb8)[i] = (unsigned)p;
    }
    if (i < 4096)       ((ushort4*)Wb)[i]        = pack4(((const float4*)W)[i]);
    else if (i < 8192)  ((ushort4*)Mb)[i - 4096] = pack4(((const float4*)M)[i - 4096]);
    if (i < D) rs[i * RS_STRIDE] = 0.0f;
    if (i == 0) *done = 0u;
    if (i < E) {
        int s = seg[i];
        if (i == 0) {
            for (int n = 0; n <= s; ++n) row_ptr[n] = 0;
        } else {
            int sp = seg[i - 1];
            for (int n = sp + 1; n <= s; ++n) row_ptr[n] = i;
        }
        if (i == E - 1) {
            for (int n = s + 1; n <= N; ++n) row_ptr[n] = E;
        }
    }
}

// -------------------------------------------------------------------------
// Fused segment-sum + MFMA matvec + relu + column-sum + (last block) softmax.
// Block = 16-node group, 512 threads / 8 waves.
// Phase A: wave w owns nodes {2w, 2w+1} fully: 8 edge streams (j) x 8 dim
//   chunks (c, 16 dims each); 4-DEEP edge unroll (avg degree 32 = exactly
//   one iteration, 4 independent row loads in flight per lane — 2x R8);
//   fp32 accum via v_cvt_pk_f32_fp8; red3 over j; bf16 rows -> swizzled
//   LDS (one wave per node: no fp32 combine pass, 8 KB LDS total).
//   j==0 lanes also gather+decode the self row -> xs.
// Phase B: wave w computes dim-tile w: X frags from LDS once, W/M from
//   global (L2-hot), 8 MFMAs, relu, column-reduce, atomicAdd into rs.
// Tail: threadfence + completion counter; last block softmaxes rs -> out
//   (rs read via atomicAdd(p,0) = device-scope coherent across XCDs).
//   Non-spinning pattern: no thread waits, non-last blocks exit.
// A-frag: A[m=lane&15][k=quad*8+j]; B[k][n=lane&15]=W[n][k]; C/D: col=dim,
// row=quad*4+reg (node).
__global__ __launch_bounds__(512) void fused_kernel(
    const int* __restrict__ node_ids, const int* __restrict__ nbr,
    const int* __restrict__ row_ptr, const unsigned char* __restrict__ emb8,
    const unsigned short* __restrict__ Wb, const unsigned short* __restrict__ Mb,
    float* __restrict__ rs, unsigned* __restrict__ done,
    float* __restrict__ out, int N) {
    __shared__ unsigned short xs[16 * D];    // self rows (bf16, swizzled)
    __shared__ unsigned short as_[16 * D];   // agg rows  (bf16, swizzled)
    __shared__ int last;

    int t = threadIdx.x;
    int w = t >> 6;          // wave 0..7
    int tt = t & 63;
    int g = blockIdx.x;      // 16-node group

    {   // ---- Phase A: wave w aggregates nodes 2w, 2w+1 (4-deep) ----
        int c = tt & 7;      // dim chunk: owns dims [16c, 16c+16)
        int j = tt >> 3;     // edge stream 0..7
        for (int i = 0; i < 2; ++i) {
            int r = w * 2 + i;           // local row 0..15
            int n = g * 16 + r;
            bool valid = n < N;

            // self row: j==0 lanes, issued early to overlap the edge loop
            uint4 xv = make_uint4(0u, 0u, 0u, 0u);   // fp8 0x00 == 0.0f
            if (valid && j == 0)
                xv = *(const uint4*)(emb8 + (size_t)node_ids[n] * D + c * 16);

            float s[16];
#pragma unroll
            for (int k = 0; k < 16; ++k) s[k] = 0.f;

            int lo = valid ? row_ptr[n] : 0;
            int hi = valid ? row_ptr[n + 1] : 0;
            int e = lo + j;
            for (; e + 24 < hi; e += 32) {       // 4 rows in flight per lane
                int i0 = nbr[e];
                int i1 = nbr[e + 8];
                int i2 = nbr[e + 16];
                int i3 = nbr[e + 24];
                uint4 a = *(const uint4*)(emb8 + (size_t)i0 * D + c * 16);
                uint4 b = *(const uint4*)(emb8 + (size_t)i1 * D + c * 16);
                uint4 d = *(const uint4*)(emb8 + (size_t)i2 * D + c * 16);
                uint4 f = *(const uint4*)(emb8 + (size_t)i3 * D + c * 16);
                acc16(a, s); acc16(b, s); acc16(d, s); acc16(f, s);
            }
            if (e + 8 < hi) {                    // 2-deep remainder
                int i0 = nbr[e];
                int i1 = nbr[e + 8];
                uint4 a = *(const uint4*)(emb8 + (size_t)i0 * D + c * 16);
                uint4 b = *(const uint4*)(emb8 + (size_t)i1 * D + c * 16);
                acc16(a, s); acc16(b, s);
                e += 16;
            }
            if (e < hi) {                        // 1-deep remainder
                uint4 a = *(const uint4*)(emb8 + (size_t)nbr[e] * D + c * 16);
                acc16(a, s);
            }
#pragma unroll
            for (int k = 0; k < 16; ++k) red3(s[k]);

            if (j == 0) {
                u16x8 o0, o1;
#pragma unroll
                for (int k = 0; k < 8; ++k) { o0[k] = f2bf(s[k]); o1[k] = f2bf(s[k + 8]); }
                *(u16x8*)&as_[swz(r, 2 * c)]     = o0;
                *(u16x8*)&as_[swz(r, 2 * c + 1)] = o1;

                float x[16];
#pragma unroll
                for (int k = 0; k < 16; ++k) x[k] = 0.f;
                acc16(xv, x);
                u16x8 p0, p1;
#pragma unroll
                for (int k = 0; k < 8; ++k) { p0[k] = f2bf(x[k]); p1[k] = f2bf(x[k + 8]); }
                *(u16x8*)&xs[swz(r, 2 * c)]     = p0;
                *(u16x8*)&xs[swz(r, 2 * c + 1)] = p1;
            }
        }
    }
    __syncthreads();

    // ---- Phase B: wave w computes dim-tile w ----
    int quad = tt >> 4, col = tt & 15;
    bf16x8 ax[4], aa[4];
#pragma unroll
    for (int ks = 0; ks < 4; ++ks) {             // elements ks*32 + quad*8 .. +8
        ax[ks] = *(const bf16x8*)&xs[swz(col, ks * 4 + quad)];
        aa[ks] = *(const bf16x8*)&as_[swz(col, ks * 4 + quad)];
    }
    int wrow = (w * 16 + col) * D + quad * 8;
    f32x4 acc = {0.f, 0.f, 0.f, 0.f};
#pragma unroll
    for (int ks = 0; ks < 4; ++ks) {
        bf16x8 bw = *(const bf16x8*)(Wb + wrow + ks * 32);
        bf16x8 bm = *(const bf16x8*)(Mb + wrow + ks * 32);
        acc = __builtin_amdgcn_mfma_f32_16x16x32_bf16(ax[ks], bw, acc, 0, 0, 0);
        acc = __builtin_amdgcn_mfma_f32_16x16x32_bf16(aa[ks], bm, acc, 0, 0, 0);
    }
    float v = fmaxf(acc[0], 0.f) + fmaxf(acc[1], 0.f)
            + fmaxf(acc[2], 0.f) + fmaxf(acc[3], 0.f);
    v += __shfl_xor(v, 16);
    v += __shfl_xor(v, 32);
    if (tt < 16) atomicAdd(&rs[(w * 16 + col) * RS_STRIDE], v);

    // ---- Completion tail: last block runs the softmax ----
    __threadfence();
    __syncthreads();
    if (t == 0) last = (atomicAdd(done, 1u) == gridDim.x - 1) ? 1 : 0;
    __syncthreads();
    if (last && t < 64) {
        float v0 = atomicAdd(&rs[t * RS_STRIDE], 0.0f);          // coherent read
        float v1 = atomicAdd(&rs[(t + 64) * RS_STRIDE], 0.0f);
        float m = fmaxf(v0, v1);
        for (int o = 32; o > 0; o >>= 1) m = fmaxf(m, __shfl_xor(m, o));
        float e0 = expf(v0 - m);
        float e1 = expf(v1 - m);
        float su = e0 + e1;
        for (int o = 32; o > 0; o >>= 1) su += __shfl_xor(su, o);
        float inv = 1.0f / su;
        out[t] = e0 * inv;
        out[t + 64] = e1 * inv;
    }
}

// -------------------------------------------------------------------------
// Fallback path (ws too small for fp8 emb table): proven fp32 kernels.
__global__ void agg_f32_kernel(const int* __restrict__ nbr, const int* __restrict__ row_ptr,
                               const float* __restrict__ emb,
                               unsigned short* __restrict__ aggb, int N) {
    int n = blockIdx.x * 4 + (threadIdx.x >> 6);
    if (n >= N) return;
    int tt = threadIdx.x & 63;
    int c = tt & 7;
    int j = tt >> 3;

    int lo = row_ptr[n], hi = row_ptr[n + 1];

    float4 s0 = make_float4(0.f, 0.f, 0.f, 0.f);
    float4 s1 = make_float4(0.f, 0.f, 0.f, 0.f);
    float4 s2 = make_float4(0.f, 0.f, 0.f, 0.f);
    float4 s3 = make_float4(0.f, 0.f, 0.f, 0.f);
    for (int e = lo + j; e < hi; e += 8) {
        const float4* r = (const float4*)&emb[(size_t)nbr[e] * D];
        float4 v0 = r[c], v1 = r[c + 8], v2 = r[c + 16], v3 = r[c + 24];
        s0.x += v0.x; s0.y += v0.y; s0.z += v0.z; s0.w += v0.w;
        s1.x += v1.x; s1.y += v1.y; s1.z += v1.z; s1.w += v1.w;
        s2.x += v2.x; s2.y += v2.y; s2.z += v2.z; s2.w += v2.w;
        s3.x += v3.x; s3.y += v3.y; s3.z += v3.z; s3.w += v3.w;
    }
    red3(s0.x); red3(s0.y); red3(s0.z); red3(s0.w);
    red3(s1.x); red3(s1.y); red3(s1.z); red3(s1.w);
    red3(s2.x); red3(s2.y); red3(s2.z); red3(s2.w);
    red3(s3.x); red3(s3.y); red3(s3.z); red3(s3.w);
    if (j == 0) {
        ushort4* o = (ushort4*)(aggb + (size_t)n * D);
        o[c]      = pack4(s0);
        o[c + 8]  = pack4(s1);
        o[c + 16] = pack4(s2);
        o[c + 24] = pack4(s3);
    }
}

__global__ __launch_bounds__(256) void matvec_f32_kernel(
    const int* __restrict__ node_ids, const float* __restrict__ emb,
    const unsigned short* __restrict__ aggb,
    const unsigned short* __restrict__ Wb, const unsigned short* __restrict__ Mb,
    float* __restrict__ rs, int N, int ngroups, int nstripes) {
    int t = threadIdx.x;
    int wid = blockIdx.x * 4 + (t >> 6);
    int l = t & 63;
    int quad = l >> 4, col = l & 15;
    int dt = wid & 7;
    int stripe = wid >> 3;

    bf16x8 bw[4], bm[4];
    int wrow = (dt * 16 + col) * D;
#pragma unroll
    for (int ks = 0; ks < 4; ++ks) {
        int off = wrow + ks * 32 + quad * 8;
        bw[ks] = *(const bf16x8*)(Wb + off);
        bm[ks] = *(const bf16x8*)(Mb + off);
    }

    const bf16x8 zero8 = {0, 0, 0, 0, 0, 0, 0, 0};
    float vsum = 0.f;

    for (int grp = stripe; grp < ngroups; grp += nstripes) {
        int node = grp * 16 + col;
        bool valid = node < N;
        int nid = valid ? node_ids[node] : 0;
        const unsigned short* ar = aggb + (size_t)node * D + quad * 8;

        f32x4 acc = {0.f, 0.f, 0.f, 0.f};
#pragma unroll
        for (int ks = 0; ks < 4; ++ks) {
            bf16x8 ax;
            if (valid) {
                const float4* xf = (const float4*)(emb +
                                   (size_t)nid * D + quad * 8 + ks * 32);
                ushort4 p0 = pack4(xf[0]);
                ushort4 p1 = pack4(xf[1]);
                ax[0] = (short)p0.x; ax[1] = (short)p0.y;
                ax[2] = (short)p0.z; ax[3] = (short)p0.w;
                ax[4] = (short)p1.x; ax[5] = (short)p1.y;
                ax[6] = (short)p1.z; ax[7] = (short)p1.w;
            } else ax = zero8;
            bf16x8 aa = valid ? *(const bf16x8*)(ar + ks * 32) : zero8;
            acc = __builtin_amdgcn_mfma_f32_16x16x32_bf16(ax, bw[ks], acc, 0, 0, 0);
            acc = __builtin_amdgcn_mfma_f32_16x16x32_bf16(aa, bm[ks], acc, 0, 0, 0);
        }
        vsum += fmaxf(acc[0], 0.f) + fmaxf(acc[1], 0.f)
              + fmaxf(acc[2], 0.f) + fmaxf(acc[3], 0.f);
    }

    vsum += __shfl_xor(vsum, 16);
    vsum += __shfl_xor(vsum, 32);
    if (l < 16) atomicAdd(&rs[(dt * 16 + col) * RS_STRIDE], vsum);
}

// -------------------------------------------------------------------------
__global__ void softmax_kernel(const float* __restrict__ rs, float* __restrict__ out) {
    int t = threadIdx.x;                 // 0..63
    float v0 = rs[t * RS_STRIDE];
    float v1 = rs[(t + 64) * RS_STRIDE];
    float m = fmaxf(v0, v1);
    for (int o = 32; o > 0; o >>= 1) m = fmaxf(m, __shfl_xor(m, o));
    float e0 = expf(v0 - m);
    float e1 = expf(v1 - m);
    float s = e0 + e1;
    for (int o = 32; o > 0; o >>= 1) s += __shfl_xor(s, o);
    float inv = 1.0f / s;
    out[t] = e0 * inv;
    out[t + 64] = e1 * inv;
}

extern "C" void kernel_launch(void* const* d_in, const int* in_sizes, int n_in,
                              void* d_out, int out_size, void* d_ws, size_t ws_size,
                              hipStream_t stream) {
    const int*   node_ids = (const int*)d_in[0];
    const int*   nbr      = (const int*)d_in[1];
    const int*   seg      = (const int*)d_in[2];
    const float* W        = (const float*)d_in[3];
    const float* M        = (const float*)d_in[4];
    const float* emb      = (const float*)d_in[5];
    float* out = (float*)d_out;

    int N = in_sizes[0];
    int E = in_sizes[1];
    long long VD = in_sizes[5];          // V*D elements
    int ngroups  = (N + 15) / 16;

    // ws: aggb[N*D] u16 | Wb | Mb | rs fp32 | row_ptr int | emb8[VD] u8 | done
    unsigned short* aggb = (unsigned short*)d_ws;
    unsigned short* Wb   = aggb + (size_t)N * D;
    unsigned short* Mb   = Wb + D * D;
    float* rs            = (float*)(Mb + D * D);
    int* row_ptr         = (int*)(rs + (size_t)D * RS_STRIDE);
    unsigned char* emb8  = (unsigned char*)(row_ptr + (N + 1));
    unsigned* done       = (unsigned*)(emb8 + VD);

    size_t need_fp8 = (size_t)((char*)emb8 - (char*)d_ws) + (size_t)VD + 16;
    bool use_fp8 = ws_size >= need_fp8;
    int n4 = use_fp8 ? (int)(VD / 4) : 0;
    int cvt_n = (n4 > 8192 ? n4 : 8192);
    int prep_n = (cvt_n > E ? cvt_n : E);

    prep_kernel<<<(prep_n + 255) / 256, 256, 0, stream>>>(emb, W, M, seg, emb8, Wb, Mb,
                                                          rs, row_ptr, done, n4, E, N);
    if (use_fp8) {
        fused_kernel<<<ngroups, 512, 0, stream>>>(node_ids, nbr, row_ptr, emb8,
                                                  Wb, Mb, rs, done, out, N);
    } else {
        int nstripes = (ngroups + 1) / 2;
        agg_f32_kernel<<<(N + 3) / 4, 256, 0, stream>>>(nbr, row_ptr, emb, aggb, N);
        matvec_f32_kernel<<<2 * nstripes, 256, 0, stream>>>(node_ids, emb, aggb, Wb, Mb,
                                                            rs, N, ngroups, nstripes);
        softmax_kernel<<<1, 64, 0, stream>>>(rs, out);
    }
}

// Round 11
// 139.761 us; speedup vs baseline: 2.2267x; 2.2267x over previous
//
#include <hip/hip_runtime.h>

#define D 128
#define RS_STRIDE 64      // floats (256 B) between result slots

typedef __attribute__((ext_vector_type(8))) short bf16x8;
typedef __attribute__((ext_vector_type(8))) unsigned short u16x8;
typedef __attribute__((ext_vector_type(4))) float f32x4;
typedef __attribute__((ext_vector_type(2))) float f32x2;

__device__ __forceinline__ unsigned short f2bf(float f) {
    unsigned u = __float_as_uint(f);
    unsigned r = (u + 0x7fffu + ((u >> 16) & 1u)) >> 16;
    return (unsigned short)r;
}
__device__ __forceinline__ ushort4 pack4(float4 v) {
    ushort4 o; o.x = f2bf(v.x); o.y = f2bf(v.y); o.z = f2bf(v.z); o.w = f2bf(v.w);
    return o;
}
__device__ __forceinline__ void red3(float& x) {
    x += __shfl_xor(x, 8);
    x += __shfl_xor(x, 16);
    x += __shfl_xor(x, 32);
}
// fp8 e4m3 x4 (one dword) decode-accumulate into 4 fp32 slots (HW cvt).
__device__ __forceinline__ void acc4(unsigned v, float* s) {
    f32x2 lo = __builtin_amdgcn_cvt_pk_f32_fp8(v, false);
    f32x2 hi = __builtin_amdgcn_cvt_pk_f32_fp8(v, true);
    s[0] += lo[0]; s[1] += lo[1]; s[2] += hi[0]; s[3] += hi[1];
}
__device__ __forceinline__ void acc16(uint4 v, float* s) {
    acc4(v.x, s); acc4(v.y, s + 4); acc4(v.z, s + 8); acc4(v.w, s + 12);
}
// LDS tile swizzle: 16B slot s (0..15) of row r -> slot s^(r&7).
__device__ __forceinline__ int swz(int r, int s) {
    return r * D + ((s ^ (r & 7)) << 3);     // ushort index
}

// -------------------------------------------------------------------------
// Fused prep: emb fp32->fp8 e4m3 row-major (if n4>0), W/M fp32->bf16,
// zero rs slots, row_ptr[N+1] from sorted segment_ids.
__global__ void prep_kernel(const float* __restrict__ emb, const float* __restrict__ W,
                            const float* __restrict__ M, const int* __restrict__ seg,
                            unsigned char* __restrict__ emb8,
                            unsigned short* __restrict__ Wb, unsigned short* __restrict__ Mb,
                            float* __restrict__ rs, int* __restrict__ row_ptr,
                            int n4, int E, int N) {
    int i = blockIdx.x * blockDim.x + threadIdx.x;
    if (i < n4) {
        float4 v = ((const float4*)emb)[i];
        int p = __builtin_amdgcn_cvt_pk_fp8_f32(v.x, v.y, 0, false);
        p = __builtin_amdgcn_cvt_pk_fp8_f32(v.z, v.w, p, true);
        ((unsigned*)emb8)[i] = (unsigned)p;
    }
    if (i < 4096)       ((ushort4*)Wb)[i]        = pack4(((const float4*)W)[i]);
    else if (i < 8192)  ((ushort4*)Mb)[i - 4096] = pack4(((const float4*)M)[i - 4096]);
    if (i < D) rs[i * RS_STRIDE] = 0.0f;
    if (i < E) {
        int s = seg[i];
        if (i == 0) {
            for (int n = 0; n <= s; ++n) row_ptr[n] = 0;
        } else {
            int sp = seg[i - 1];
            for (int n = sp + 1; n <= s; ++n) row_ptr[n] = i;
        }
        if (i == E - 1) {
            for (int n = s + 1; n <= N; ++n) row_ptr[n] = E;
        }
    }
}

// -------------------------------------------------------------------------
// Fused segment-sum + MFMA matvec + relu + column-sum.
// Block = 16-node group, 512 threads / 8 waves. NO device fence / tail
// (R10 lesson: per-block __threadfence() = buffer_wbl2 storm, 5x slowdown).
// Phase A: wave w owns nodes {2w, 2w+1} fully: 8 edge streams (j) x 8 dim
//   chunks (c, 16 dims each); 4-DEEP edge unroll (avg degree 32 = one
//   iteration, 4 independent row loads in flight per lane — 2x R8);
//   fp32 accum via v_cvt_pk_f32_fp8; red3 over j; bf16 rows -> swizzled
//   LDS (one wave per node: no fp32 combine pass, 8 KB LDS total).
//   j==0 lanes also gather+decode the self row -> xs.
// Phase B: wave w computes dim-tile w: X frags from LDS once, W/M from
//   global (L2-hot), 8 MFMAs, relu, column-reduce, atomicAdd into rs.
// A-frag: A[m=lane&15][k=quad*8+j]; B[k][n=lane&15]=W[n][k]; C/D: col=dim,
// row=quad*4+reg (node).
__global__ __launch_bounds__(512) void fused_kernel(
    const int* __restrict__ node_ids, const int* __restrict__ nbr,
    const int* __restrict__ row_ptr, const unsigned char* __restrict__ emb8,
    const unsigned short* __restrict__ Wb, const unsigned short* __restrict__ Mb,
    float* __restrict__ rs, int N) {
    __shared__ unsigned short xs[16 * D];    // self rows (bf16, swizzled)
    __shared__ unsigned short as_[16 * D];   // agg rows  (bf16, swizzled)

    int t = threadIdx.x;
    int w = t >> 6;          // wave 0..7
    int tt = t & 63;
    int g = blockIdx.x;      // 16-node group

    {   // ---- Phase A: wave w aggregates nodes 2w, 2w+1 (4-deep) ----
        int c = tt & 7;      // dim chunk: owns dims [16c, 16c+16)
        int j = tt >> 3;     // edge stream 0..7
        for (int i = 0; i < 2; ++i) {
            int r = w * 2 + i;           // local row 0..15
            int n = g * 16 + r;
            bool valid = n < N;

            // self row: j==0 lanes, issued early to overlap the edge loop
            uint4 xv = make_uint4(0u, 0u, 0u, 0u);   // fp8 0x00 == 0.0f
            if (valid && j == 0)
                xv = *(const uint4*)(emb8 + (size_t)node_ids[n] * D + c * 16);

            float s[16];
#pragma unroll
            for (int k = 0; k < 16; ++k) s[k] = 0.f;

            int lo = valid ? row_ptr[n] : 0;
            int hi = valid ? row_ptr[n + 1] : 0;
            int e = lo + j;
            for (; e + 24 < hi; e += 32) {       // 4 rows in flight per lane
                int i0 = nbr[e];
                int i1 = nbr[e + 8];
                int i2 = nbr[e + 16];
                int i3 = nbr[e + 24];
                uint4 a = *(const uint4*)(emb8 + (size_t)i0 * D + c * 16);
                uint4 b = *(const uint4*)(emb8 + (size_t)i1 * D + c * 16);
                uint4 d = *(const uint4*)(emb8 + (size_t)i2 * D + c * 16);
                uint4 f = *(const uint4*)(emb8 + (size_t)i3 * D + c * 16);
                acc16(a, s); acc16(b, s); acc16(d, s); acc16(f, s);
            }
            if (e + 8 < hi) {                    // 2-deep remainder
                int i0 = nbr[e];
                int i1 = nbr[e + 8];
                uint4 a = *(const uint4*)(emb8 + (size_t)i0 * D + c * 16);
                uint4 b = *(const uint4*)(emb8 + (size_t)i1 * D + c * 16);
                acc16(a, s); acc16(b, s);
                e += 16;
            }
            if (e < hi) {                        // 1-deep remainder
                uint4 a = *(const uint4*)(emb8 + (size_t)nbr[e] * D + c * 16);
                acc16(a, s);
            }
#pragma unroll
            for (int k = 0; k < 16; ++k) red3(s[k]);

            if (j == 0) {
                u16x8 o0, o1;
#pragma unroll
                for (int k = 0; k < 8; ++k) { o0[k] = f2bf(s[k]); o1[k] = f2bf(s[k + 8]); }
                *(u16x8*)&as_[swz(r, 2 * c)]     = o0;
                *(u16x8*)&as_[swz(r, 2 * c + 1)] = o1;

                float x[16];
#pragma unroll
                for (int k = 0; k < 16; ++k) x[k] = 0.f;
                acc16(xv, x);
                u16x8 p0, p1;
#pragma unroll
                for (int k = 0; k < 8; ++k) { p0[k] = f2bf(x[k]); p1[k] = f2bf(x[k + 8]); }
                *(u16x8*)&xs[swz(r, 2 * c)]     = p0;
                *(u16x8*)&xs[swz(r, 2 * c + 1)] = p1;
            }
        }
    }
    __syncthreads();

    // ---- Phase B: wave w computes dim-tile w ----
    int quad = tt >> 4, col = tt & 15;
    bf16x8 ax[4], aa[4];
#pragma unroll
    for (int ks = 0; ks < 4; ++ks) {             // elements ks*32 + quad*8 .. +8
        ax[ks] = *(const bf16x8*)&xs[swz(col, ks * 4 + quad)];
        aa[ks] = *(const bf16x8*)&as_[swz(col, ks * 4 + quad)];
    }
    int wrow = (w * 16 + col) * D + quad * 8;
    f32x4 acc = {0.f, 0.f, 0.f, 0.f};
#pragma unroll
    for (int ks = 0; ks < 4; ++ks) {
        bf16x8 bw = *(const bf16x8*)(Wb + wrow + ks * 32);
        bf16x8 bm = *(const bf16x8*)(Mb + wrow + ks * 32);
        acc = __builtin_amdgcn_mfma_f32_16x16x32_bf16(ax[ks], bw, acc, 0, 0, 0);
        acc = __builtin_amdgcn_mfma_f32_16x16x32_bf16(aa[ks], bm, acc, 0, 0, 0);
    }
    float v = fmaxf(acc[0], 0.f) + fmaxf(acc[1], 0.f)
            + fmaxf(acc[2], 0.f) + fmaxf(acc[3], 0.f);
    v += __shfl_xor(v, 16);
    v += __shfl_xor(v, 32);
    if (tt < 16) atomicAdd(&rs[(w * 16 + col) * RS_STRIDE], v);
}

// -------------------------------------------------------------------------
// Fallback path (ws too small for fp8 emb table): proven fp32 kernels.
__global__ void agg_f32_kernel(const int* __restrict__ nbr, const int* __restrict__ row_ptr,
                               const float* __restrict__ emb,
                               unsigned short* __restrict__ aggb, int N) {
    int n = blockIdx.x * 4 + (threadIdx.x >> 6);
    if (n >= N) return;
    int tt = threadIdx.x & 63;
    int c = tt & 7;
    int j = tt >> 3;

    int lo = row_ptr[n], hi = row_ptr[n + 1];

    float4 s0 = make_float4(0.f, 0.f, 0.f, 0.f);
    float4 s1 = make_float4(0.f, 0.f, 0.f, 0.f);
    float4 s2 = make_float4(0.f, 0.f, 0.f, 0.f);
    float4 s3 = make_float4(0.f, 0.f, 0.f, 0.f);
    for (int e = lo + j; e < hi; e += 8) {
        const float4* r = (const float4*)&emb[(size_t)nbr[e] * D];
        float4 v0 = r[c], v1 = r[c + 8], v2 = r[c + 16], v3 = r[c + 24];
        s0.x += v0.x; s0.y += v0.y; s0.z += v0.z; s0.w += v0.w;
        s1.x += v1.x; s1.y += v1.y; s1.z += v1.z; s1.w += v1.w;
        s2.x += v2.x; s2.y += v2.y; s2.z += v2.z; s2.w += v2.w;
        s3.x += v3.x; s3.y += v3.y; s3.z += v3.z; s3.w += v3.w;
    }
    red3(s0.x); red3(s0.y); red3(s0.z); red3(s0.w);
    red3(s1.x); red3(s1.y); red3(s1.z); red3(s1.w);
    red3(s2.x); red3(s2.y); red3(s2.z); red3(s2.w);
    red3(s3.x); red3(s3.y); red3(s3.z); red3(s3.w);
    if (j == 0) {
        ushort4* o = (ushort4*)(aggb + (size_t)n * D);
        o[c]      = pack4(s0);
        o[c + 8]  = pack4(s1);
        o[c + 16] = pack4(s2);
        o[c + 24] = pack4(s3);
    }
}

__global__ __launch_bounds__(256) void matvec_f32_kernel(
    const int* __restrict__ node_ids, const float* __restrict__ emb,
    const unsigned short* __restrict__ aggb,
    const unsigned short* __restrict__ Wb, const unsigned short* __restrict__ Mb,
    float* __restrict__ rs, int N, int ngroups, int nstripes) {
    int t = threadIdx.x;
    int wid = blockIdx.x * 4 + (t >> 6);
    int l = t & 63;
    int quad = l >> 4, col = l & 15;
    int dt = wid & 7;
    int stripe = wid >> 3;

    bf16x8 bw[4], bm[4];
    int wrow = (dt * 16 + col) * D;
#pragma unroll
    for (int ks = 0; ks < 4; ++ks) {
        int off = wrow + ks * 32 + quad * 8;
        bw[ks] = *(const bf16x8*)(Wb + off);
        bm[ks] = *(const bf16x8*)(Mb + off);
    }

    const bf16x8 zero8 = {0, 0, 0, 0, 0, 0, 0, 0};
    float vsum = 0.f;

    for (int grp = stripe; grp < ngroups; grp += nstripes) {
        int node = grp * 16 + col;
        bool valid = node < N;
        int nid = valid ? node_ids[node] : 0;
        const unsigned short* ar = aggb + (size_t)node * D + quad * 8;

        f32x4 acc = {0.f, 0.f, 0.f, 0.f};
#pragma unroll
        for (int ks = 0; ks < 4; ++ks) {
            bf16x8 ax;
            if (valid) {
                const float4* xf = (const float4*)(emb +
                                   (size_t)nid * D + quad * 8 + ks * 32);
                ushort4 p0 = pack4(xf[0]);
                ushort4 p1 = pack4(xf[1]);
                ax[0] = (short)p0.x; ax[1] = (short)p0.y;
                ax[2] = (short)p0.z; ax[3] = (short)p0.w;
                ax[4] = (short)p1.x; ax[5] = (short)p1.y;
                ax[6] = (short)p1.z; ax[7] = (short)p1.w;
            } else ax = zero8;
            bf16x8 aa = valid ? *(const bf16x8*)(ar + ks * 32) : zero8;
            acc = __builtin_amdgcn_mfma_f32_16x16x32_bf16(ax, bw[ks], acc, 0, 0, 0);
            acc = __builtin_amdgcn_mfma_f32_16x16x32_bf16(aa, bm[ks], acc, 0, 0, 0);
        }
        vsum += fmaxf(acc[0], 0.f) + fmaxf(acc[1], 0.f)
              + fmaxf(acc[2], 0.f) + fmaxf(acc[3], 0.f);
    }

    vsum += __shfl_xor(vsum, 16);
    vsum += __shfl_xor(vsum, 32);
    if (l < 16) atomicAdd(&rs[(dt * 16 + col) * RS_STRIDE], vsum);
}

// -------------------------------------------------------------------------
__global__ void softmax_kernel(const float* __restrict__ rs, float* __restrict__ out) {
    int t = threadIdx.x;                 // 0..63
    float v0 = rs[t * RS_STRIDE];
    float v1 = rs[(t + 64) * RS_STRIDE];
    float m = fmaxf(v0, v1);
    for (int o = 32; o > 0; o >>= 1) m = fmaxf(m, __shfl_xor(m, o));
    float e0 = expf(v0 - m);
    float e1 = expf(v1 - m);
    float s = e0 + e1;
    for (int o = 32; o > 0; o >>= 1) s += __shfl_xor(s, o);
    float inv = 1.0f / s;
    out[t] = e0 * inv;
    out[t + 64] = e1 * inv;
}

extern "C" void kernel_launch(void* const* d_in, const int* in_sizes, int n_in,
                              void* d_out, int out_size, void* d_ws, size_t ws_size,
                              hipStream_t stream) {
    const int*   node_ids = (const int*)d_in[0];
    const int*   nbr      = (const int*)d_in[1];
    const int*   seg      = (const int*)d_in[2];
    const float* W        = (const float*)d_in[3];
    const float* M        = (const float*)d_in[4];
    const float* emb      = (const float*)d_in[5];
    float* out = (float*)d_out;

    int N = in_sizes[0];
    int E = in_sizes[1];
    long long VD = in_sizes[5];          // V*D elements
    int ngroups  = (N + 15) / 16;

    // ws layout: aggb[N*D] u16 | Wb | Mb | rs fp32 | row_ptr int | emb8[VD] u8
    unsigned short* aggb = (unsigned short*)d_ws;
    unsigned short* Wb   = aggb + (size_t)N * D;
    unsigned short* Mb   = Wb + D * D;
    float* rs            = (float*)(Mb + D * D);
    int* row_ptr         = (int*)(rs + (size_t)D * RS_STRIDE);
    unsigned char* emb8  = (unsigned char*)(row_ptr + (N + 1));

    size_t need_fp8 = (size_t)((char*)emb8 - (char*)d_ws) + (size_t)VD;
    bool use_fp8 = ws_size >= need_fp8;
    int n4 = use_fp8 ? (int)(VD / 4) : 0;
    int cvt_n = (n4 > 8192 ? n4 : 8192);
    int prep_n = (cvt_n > E ? cvt_n : E);

    prep_kernel<<<(prep_n + 255) / 256, 256, 0, stream>>>(emb, W, M, seg, emb8, Wb, Mb,
                                                          rs, row_ptr, n4, E, N);
    if (use_fp8) {
        fused_kernel<<<ngroups, 512, 0, stream>>>(node_ids, nbr, row_ptr, emb8,
                                                  Wb, Mb, rs, N);
    } else {
        int nstripes = (ngroups + 1) / 2;
        agg_f32_kernel<<<(N + 3) / 4, 256, 0, stream>>>(nbr, row_ptr, emb, aggb, N);
        matvec_f32_kernel<<<2 * nstripes, 256, 0, stream>>>(node_ids, emb, aggb, Wb, Mb,
                                                            rs, N, ngroups, nstripes);
    }
    softmax_kernel<<<1, 64, 0, stream>>>(rs, out);
}